// Round 13
// baseline (361.953 us; speedup 1.0000x reference)
//
#include <hip/hip_runtime.h>
#include <hip/hip_bf16.h>
#include <cstdint>
#include <cstddef>

// Problem: B=64, L=2048, E=1024, A=512
#define BB   64
#define LL   2048
#define ED   1024
#define AD   512
#define BM   128          // l-rows per block
#define NCH  (LL / BM)    // 16 chunks per batch row
#define KST  32           // 32 K-steps of BK=32

typedef short  short8  __attribute__((ext_vector_type(8)));
typedef float  f32x4   __attribute__((ext_vector_type(4)));

__device__ __forceinline__ unsigned short f2bf(float x) {
  unsigned u = __float_as_uint(x);
  u += 0x7FFFu + ((u >> 16) & 1u);
  return (unsigned short)(u >> 16);
}

// pack 8 fp32 -> 8 bf16 (RNE) via v_cvt_pk_bf16_f32
__device__ __forceinline__ short8 cvt8(f32x4 lo, f32x4 hi) {
  union { short8 s; unsigned u[4]; } r;
  asm("v_cvt_pk_bf16_f32 %0, %1, %2" : "=v"(r.u[0]) : "v"(lo[0]), "v"(lo[1]));
  asm("v_cvt_pk_bf16_f32 %0, %1, %2" : "=v"(r.u[1]) : "v"(lo[2]), "v"(lo[3]));
  asm("v_cvt_pk_bf16_f32 %0, %1, %2" : "=v"(r.u[2]) : "v"(hi[0]), "v"(hi[1]));
  asm("v_cvt_pk_bf16_f32 %0, %1, %2" : "=v"(r.u[3]) : "v"(hi[2]), "v"(hi[3]));
  return r.s;
}

#define GLOAD_LDS16(gp, lp)                                                        \
  __builtin_amdgcn_global_load_lds(                                                \
      (const __attribute__((address_space(1))) unsigned int*)(gp),                 \
      (__attribute__((address_space(3))) unsigned int*)(lp), 16, 0, 0)

// ---------------- kernel 0: prep (unchanged, verified) ----------------
// blocks 0..63   : dec_proj row b = dec[b] @ W_dec + b_dec
// blocks 64..191 : pack W_enc fp32 -> bf16 in frag-contiguous layout:
//   o = ks*16384 + cblk*512 + kg*128 + r*8 + j ; k = ks*32+kg*8+j, col = cblk*16+r
__global__ __launch_bounds__(512) void prep_kernel(
    const float* __restrict__ W_enc, const float* __restrict__ dec,
    const float* __restrict__ W_dec, const float* __restrict__ b_dec,
    unsigned short* __restrict__ Wb, float* __restrict__ dp) {
  const int blk = blockIdx.x, t = threadIdx.x;
  if (blk < BB) {
    const float* drow = dec + blk * ED;
    float a0 = 0.f, a1 = 0.f, a2 = 0.f, a3 = 0.f;
    for (int k = 0; k < ED; k += 4) {
      a0 = fmaf(drow[k],     W_dec[(k)     * AD + t], a0);
      a1 = fmaf(drow[k + 1], W_dec[(k + 1) * AD + t], a1);
      a2 = fmaf(drow[k + 2], W_dec[(k + 2) * AD + t], a2);
      a3 = fmaf(drow[k + 3], W_dec[(k + 3) * AD + t], a3);
    }
    dp[blk * AD + t] = (a0 + a1) + (a2 + a3) + b_dec[t];
  } else {
    const int base = (blk - BB) * 4096;
#pragma unroll
    for (int ii = 0; ii < 8; ii++) {
      const int o    = base + ii * 512 + t;
      const int ks   = o >> 14;
      const int cblk = (o >> 9) & 31;
      const int kg   = (o >> 7) & 3;
      const int r    = (o >> 3) & 15;
      const int j    = o & 7;
      const int k    = ks * 32 + kg * 8 + j;
      const int c    = cblk * 16 + r;
      Wb[o] = f2bf(W_enc[k * AD + c]);
    }
  }
}

// ---------------- kernel 1: fused GEMM + tanh-score + softmax partials ----------
// grid (NCH=16, BB), 512 threads = 8 waves (2M x 4N), wave tile 64 x 128.
// BYTE-RATE EXPERIMENT (nt / L1-bypass): B has NO LDS — frags stream from the
// L2-resident frag-contiguous Wb via __builtin_nontemporal_load (hypothesis:
// the ~16 B/cyc/CU VMEM cap is L1 line-fill; nt bypasses it). A staged via LDS
// (dbuf, cvt_pk), 1-iter reg lead. All waits are compiler-generated in-order
// vmcnt: cvt waits only the 2 oldest (prev A); MFMA waits B (vmcnt(2), A stays).
__global__ __launch_bounds__(512, 2) void fused_kernel(
    const float* __restrict__ sem, const unsigned short* __restrict__ Wb,
    const float* __restrict__ dp, const float* __restrict__ b_enc,
    const float* __restrict__ Wf,
    float* __restrict__ raw_scores,
    float* __restrict__ ws_ms, float* __restrict__ ws_o) {

  __shared__ unsigned short Ab[2][4096];   // [buf][rblk(8)][kg(4)][16][8] 16 KB
  __shared__ float epi[1800];              // epilogue scratch 7.2 KB

  const int t    = threadIdx.x;
  const int lane = t & 63;
  const int wave = t >> 6;
  const int wm   = wave >> 2;   // 0..1 row half
  const int wn   = wave & 3;    // 0..3 col quarter
  const int b    = blockIdx.y;
  const int chunk= blockIdx.x;
  const int l0   = chunk * BM;

  // A staging: thread -> (row srow 0..127, k-oct skg 0..3); 2 f32x4, 1 ds_write_b128
  const int srow = t >> 2;
  const int skg  = t & 3;
  const float* aptr = sem + ((size_t)(b * LL + l0 + srow)) * ED + skg * 8;
  const int awr = (srow >> 4) * 512 + skg * 128 + (srow & 15) * 8;

  // frag read bases
  const int arow = lane & 15;
  const int akg  = lane >> 4;
  const int afr  = wm * 2048 + lane * 8;                   // + mf*512 (A in Ab)
  const unsigned short* wbb = Wb + wn * 4096 + lane * 8;   // + ks*16384 + nf*512

  f32x4 acc[4][8];
#pragma unroll
  for (int i = 0; i < 4; i++)
#pragma unroll
    for (int j = 0; j < 8; j++) acc[i][j] = (f32x4)0.f;

  // ---- prologue: A(0)->cvt->Ab0; A(1) in flight ----
  f32x4 pA0 = *(const f32x4*)(aptr);
  f32x4 pA1 = *(const f32x4*)(aptr + 4);
  f32x4 qA0 = *(const f32x4*)(aptr + 32);
  f32x4 qA1 = *(const f32x4*)(aptr + 36);
  *(short8*)&Ab[0][awr] = cvt8(pA0, pA1);   // auto-waits A(0); A(1) stays in flight
  asm volatile("s_waitcnt lgkmcnt(0)" ::: "memory");
  __builtin_amdgcn_sched_barrier(0);
  __builtin_amdgcn_s_barrier();

  // ITER(ks): B nt-loads (step ks) -> A loads (ks+2) -> cvt A(ks+1)->Ab[nb]
  // (auto-wait: only the 2 oldest = prev A; B/LA unaffected) -> frags+MFMA
  // (auto vmcnt(2): B drained, LA stays) -> lgkmcnt(0)+barrier.
#define ITER(ks, CA0, CA1, LA0, LA1)                                               \
  {                                                                                \
    const int cb = (ks) & 1, nb = ((ks) + 1) & 1;                                  \
    const unsigned short* wq = wbb + (size_t)(ks) * 16384;                         \
    short8 bv0 = __builtin_nontemporal_load((const short8*)(wq));                  \
    short8 bv1 = __builtin_nontemporal_load((const short8*)(wq + 512));            \
    short8 bv2 = __builtin_nontemporal_load((const short8*)(wq + 1024));           \
    short8 bv3 = __builtin_nontemporal_load((const short8*)(wq + 1536));           \
    short8 bv4 = __builtin_nontemporal_load((const short8*)(wq + 2048));           \
    short8 bv5 = __builtin_nontemporal_load((const short8*)(wq + 2560));           \
    short8 bv6 = __builtin_nontemporal_load((const short8*)(wq + 3072));           \
    short8 bv7 = __builtin_nontemporal_load((const short8*)(wq + 3584));           \
    if ((ks) + 2 < KST) {                                                          \
      const float* ap = aptr + ((ks) + 2) * 32;                                    \
      LA0 = *(const f32x4*)(ap);                                                   \
      LA1 = *(const f32x4*)(ap + 4);                                               \
    }                                                                              \
    __builtin_amdgcn_sched_barrier(0);  /* pin: loads issued before cvt/frags */   \
    if ((ks) + 1 < KST)                                                            \
      *(short8*)&Ab[nb][awr] = cvt8(CA0, CA1);                                     \
    short8 av[4];                                                                  \
    _Pragma("unroll")                                                              \
    for (int mf = 0; mf < 4; mf++)                                                 \
      av[mf] = *(const short8*)&Ab[cb][afr + mf * 512];                            \
    __builtin_amdgcn_s_setprio(1);                                                 \
    _Pragma("unroll")                                                              \
    for (int mf = 0; mf < 4; mf++) {                                               \
      acc[mf][0] = __builtin_amdgcn_mfma_f32_16x16x32_bf16(av[mf], bv0, acc[mf][0], 0, 0, 0); \
      acc[mf][1] = __builtin_amdgcn_mfma_f32_16x16x32_bf16(av[mf], bv1, acc[mf][1], 0, 0, 0); \
      acc[mf][2] = __builtin_amdgcn_mfma_f32_16x16x32_bf16(av[mf], bv2, acc[mf][2], 0, 0, 0); \
      acc[mf][3] = __builtin_amdgcn_mfma_f32_16x16x32_bf16(av[mf], bv3, acc[mf][3], 0, 0, 0); \
      acc[mf][4] = __builtin_amdgcn_mfma_f32_16x16x32_bf16(av[mf], bv4, acc[mf][4], 0, 0, 0); \
      acc[mf][5] = __builtin_amdgcn_mfma_f32_16x16x32_bf16(av[mf], bv5, acc[mf][5], 0, 0, 0); \
      acc[mf][6] = __builtin_amdgcn_mfma_f32_16x16x32_bf16(av[mf], bv6, acc[mf][6], 0, 0, 0); \
      acc[mf][7] = __builtin_amdgcn_mfma_f32_16x16x32_bf16(av[mf], bv7, acc[mf][7], 0, 0, 0); \
    }                                                                              \
    __builtin_amdgcn_s_setprio(0);                                                 \
    asm volatile("s_waitcnt lgkmcnt(0)" ::: "memory");                             \
    __builtin_amdgcn_sched_barrier(0);                                             \
    __builtin_amdgcn_s_barrier();                                                  \
  }

  for (int kk = 0; kk < KST; kk += 2) {
    ITER(kk,     qA0, qA1, pA0, pA1);
    ITER(kk + 1, pA0, pA1, qA0, qA1);
  }
#undef ITER

  // ---- epilogue (R3-verified logic; arrays in epi) ----
  float (*sc_part)[4]   = (float (*)[4])epi;             // 128*4
  float* scores_lds     = epi + 512;                     // 128
  float* weight         = epi + 640;                     // 128
  float (*o_lds)[AD]    = (float (*)[AD])(epi + 768);    // 2*512
  float* bcv            = epi + 1792;                    // 2

  float dpv[8], wfv[8], bev[8];
#pragma unroll
  for (int nf = 0; nf < 8; nf++) {
    const int c = wn * 128 + nf * 16 + arow;
    dpv[nf] = dp[b * AD + c];
    wfv[nf] = Wf[c];
    bev[nf] = b_enc[c];
  }
#pragma unroll
  for (int mf = 0; mf < 4; mf++) {
#pragma unroll
    for (int r = 0; r < 4; r++) {
      float p = 0.f;
#pragma unroll
      for (int nf = 0; nf < 8; nf++) {
        float e = acc[mf][nf][r] + bev[nf];
        acc[mf][nf][r] = e;                      // keep enc_proj (+b_enc) for o-accum
        float x = e + dpv[nf];
        float ex = __expf(2.f * x);              // tanh via exp
        float th = 1.f - 2.f / (ex + 1.f);
        p = fmaf(th, wfv[nf], p);
      }
      p += __shfl_xor(p, 1); p += __shfl_xor(p, 2);
      p += __shfl_xor(p, 4); p += __shfl_xor(p, 8);
      if (arow == 0) sc_part[wm * 64 + mf * 16 + akg * 4 + r][wn] = p;
    }
  }
  __syncthreads();

  if (t < BM) {
    float s = sc_part[t][0] + sc_part[t][1] + sc_part[t][2] + sc_part[t][3];
    scores_lds[t] = s;
    raw_scores[(size_t)b * LL + l0 + t] = s;     // raw; finalize normalizes in place
  }
  __syncthreads();
  if (t < 64) {
    float m = fmaxf(scores_lds[t], scores_lds[t + 64]);
#pragma unroll
    for (int off = 1; off < 64; off <<= 1) m = fmaxf(m, __shfl_xor(m, off));
    if (t == 0) bcv[0] = m;
  }
  __syncthreads();
  const float m_c = bcv[0];
  if (t < BM) weight[t] = __expf(scores_lds[t] - m_c);
  __syncthreads();
  if (t < 64) {
    float s = weight[t] + weight[t + 64];
#pragma unroll
    for (int off = 1; off < 64; off <<= 1) s += __shfl_xor(s, off);
    if (t == 0) bcv[1] = s;
  }

  float wv[4][4];
#pragma unroll
  for (int mf = 0; mf < 4; mf++)
#pragma unroll
    for (int r = 0; r < 4; r++) wv[mf][r] = weight[wm * 64 + mf * 16 + akg * 4 + r];
#pragma unroll
  for (int nf = 0; nf < 8; nf++) {
    float cp = 0.f;
#pragma unroll
    for (int mf = 0; mf < 4; mf++)
#pragma unroll
      for (int r = 0; r < 4; r++) cp = fmaf(wv[mf][r], acc[mf][nf][r], cp);
    cp += __shfl_xor(cp, 16);
    cp += __shfl_xor(cp, 32);
    if (lane < 16) o_lds[wm][wn * 128 + nf * 16 + lane] = cp;
  }
  __syncthreads();
  if (t < AD)
    ws_o[((size_t)b * NCH + chunk) * AD + t] = o_lds[0][t] + o_lds[1][t];
  if (t == 0) {
    ws_ms[(b * NCH + chunk) * 2]     = m_c;
    ws_ms[(b * NCH + chunk) * 2 + 1] = bcv[1];
  }
}

// ---------------- kernel 2: finalize (merge chunk partials, normalize) ----------
__global__ __launch_bounds__(256) void finalize_kernel(
    const float* __restrict__ ws_ms, const float* __restrict__ ws_o,
    float* __restrict__ out0, float* __restrict__ outS) {
  const int b = blockIdx.x, t = threadIdx.x;
  float ms[NCH], ss[NCH];
  float M = -1e30f;
#pragma unroll
  for (int i = 0; i < NCH; i++) {
    ms[i] = ws_ms[(b * NCH + i) * 2];
    ss[i] = ws_ms[(b * NCH + i) * 2 + 1];
    M = fmaxf(M, ms[i]);
  }
  float S = 0.f, w[NCH];
#pragma unroll
  for (int i = 0; i < NCH; i++) { w[i] = __expf(ms[i] - M); S = fmaf(ss[i], w[i], S); }
  const float invS = 1.f / S;
  for (int c = t; c < AD; c += 256) {
    float a = 0.f;
#pragma unroll
    for (int i = 0; i < NCH; i++) a = fmaf(ws_o[((size_t)b * NCH + i) * AD + c], w[i], a);
    out0[b * AD + c] = a * invS;
  }
  for (int l = t; l < LL; l += 256) {
    float r = outS[(size_t)b * LL + l];
    outS[(size_t)b * LL + l] = __expf(r - M) * invS;
  }
}

extern "C" void kernel_launch(void* const* d_in, const int* in_sizes, int n_in,
                              void* d_out, int out_size, void* d_ws, size_t ws_size,
                              hipStream_t stream) {
  const float* sem    = (const float*)d_in[0];
  const float* dec    = (const float*)d_in[1];
  const float* W_enc  = (const float*)d_in[2];
  const float* b_enc  = (const float*)d_in[3];
  const float* W_dec  = (const float*)d_in[4];
  const float* b_dec  = (const float*)d_in[5];
  const float* W_full = (const float*)d_in[6];
  // d_in[7] = b_full: constant shift, cancels in softmax.

  float* out0 = (float*)d_out;            // att_output [64][512]
  float* outS = out0 + BB * AD;           // att_scores [64][2048]

  char* ws = (char*)d_ws;
  unsigned short* Wb = (unsigned short*)ws;                          // 1 MB bf16 packed W_enc
  float* dpw   = (float*)(ws + (1 << 20));                           // 128 KB dec_proj+b_dec
  float* ws_ms = (float*)(ws + (1 << 20) + (128 << 10));             // 8 KB (m,s) per chunk
  float* ws_o  = (float*)(ws + (1 << 20) + (136 << 10));             // 2 MB o partials

  prep_kernel<<<BB + 128, 512, 0, stream>>>(W_enc, dec, W_dec, b_dec, Wb, dpw);
  dim3 g1(NCH, BB);
  fused_kernel<<<g1, 512, 0, stream>>>(sem, Wb, dpw, b_enc, W_full, outS, ws_ms, ws_o);
  finalize_kernel<<<BB, 256, 0, stream>>>(ws_ms, ws_o, out0, outS);
}